// Round 7
// baseline (359.527 us; speedup 1.0000x reference)
//
#include <hip/hip_runtime.h>
#include <hip/hip_bf16.h>
#include <math.h>

// Problem constants (fixed by setup_inputs)
#define DM 1024          // d_model
#define NS 16            // d_state
#define BSZ 8
#define LSEQ 1024
#define MROWS (BSZ*LSEQ) // 8192 token rows
#define NSEG 8           // scan segments (parallel over L)
#define SEGL (LSEQ/NSEG) // 128 steps per segment
#define ROWP 132         // padded LDS row length (words), 128 + 4

typedef __bf16 bf16;
typedef bf16 bf16x8 __attribute__((ext_vector_type(8)));
typedef bf16 bf16x4 __attribute__((ext_vector_type(4)));
typedef float f32x4 __attribute__((ext_vector_type(4)));
typedef unsigned int u32;
typedef unsigned short u16;
typedef u32 u32x4 __attribute__((ext_vector_type(4)));

__device__ __forceinline__ void async16(const void* g, void* l) {
  __builtin_amdgcn_global_load_lds((const __attribute__((address_space(1))) void*)g,
                                   (__attribute__((address_space(3))) void*)l,
                                   16, 0, 0);
}

// packed (dt, xi) word: dt bf16 in low 16, xi bf16 in high 16
__device__ __forceinline__ float bflo(u32 u) { return __builtin_bit_cast(float, (u32)(u << 16)); }
__device__ __forceinline__ float bfhi(u32 u) { return __builtin_bit_cast(float, (u32)(u & 0xffff0000u)); }

// DPP row_ror add chain: 16-lane row reduction on the VALU pipe
template <int CTRL>
__device__ __forceinline__ float dpp_add(float v) {
  int x = __builtin_amdgcn_update_dpp(0, __builtin_bit_cast(int, v), CTRL, 0xf, 0xf, true);
  return v + __builtin_bit_cast(float, x);
}
__device__ __forceinline__ float row_reduce16(float p) {
  p = dpp_add<0x121>(p);
  p = dpp_add<0x122>(p);
  p = dpp_add<0x124>(p);
  p = dpp_add<0x128>(p);
  return p;               // all 16 lanes hold the row sum
}

// Segmented-scan grid decode: 4096 blocks. blk%8 = XCD (round-robin dispatch
// heuristic); 4 consecutive d-groups (= one 128B line of dt/xi/z rows) map to
// the same XCD for L2 line sharing.
__device__ __forceinline__ void seg_decode(int blk, int& s, int& b, int& d0) {
  int xcd = blk & 7, rest = blk >> 3;
  int q0 = rest & 3, q1 = (rest >> 2) & 1, sb = rest >> 3;   // sb 0..63
  int dgrp = q0 | (xcd << 2) | (q1 << 5);                    // 0..63
  s = sb >> 3; b = sb & 7; d0 = dgrp * 16;
}

// ---------------------------------------------------------------------------
// f32 -> bf16 cast (weights)
// ---------------------------------------------------------------------------
__global__ void cast_f2b(const float* __restrict__ s, bf16* __restrict__ d, int n4) {
  int i = blockIdx.x * 256 + threadIdx.x;
  if (i < n4) {
    float4 v = ((const float4*)s)[i];
    bf16x4 o;
    o.x = (bf16)v.x; o.y = (bf16)v.y; o.z = (bf16)v.z; o.w = (bf16)v.w;
    *(bf16x4*)(d + 4 * (size_t)i) = o;
  }
}

// ---------------------------------------------------------------------------
// Transpose + cast: dst[k][d] = (bf16) src[d][k], 1024x1024. 64x64 LDS tiles.
// ---------------------------------------------------------------------------
__global__ void transpose_cast(const float* __restrict__ src, bf16* __restrict__ dst) {
  __shared__ float tile[64][65];
  const int bk = blockIdx.x * 64;
  const int bd = blockIdx.y * 64;
  const int t = threadIdx.x;
  const int c4 = t & 15;
  const int r0 = t >> 4;
#pragma unroll
  for (int p = 0; p < 4; ++p) {
    int r = r0 + p * 16;
    float4 v = *(const float4*)(src + (size_t)(bd + r) * 1024 + bk + c4 * 4);
    tile[r][c4 * 4 + 0] = v.x;
    tile[r][c4 * 4 + 1] = v.y;
    tile[r][c4 * 4 + 2] = v.z;
    tile[r][c4 * 4 + 3] = v.w;
  }
  __syncthreads();
#pragma unroll
  for (int p = 0; p < 4; ++p) {
    int r = r0 + p * 16;
    bf16x4 o;
    o.x = (bf16)tile[c4 * 4 + 0][r];
    o.y = (bf16)tile[c4 * 4 + 1][r];
    o.z = (bf16)tile[c4 * 4 + 2][r];
    o.w = (bf16)tile[c4 * 4 + 3][r];
    *(bf16x4*)(dst + (size_t)(bk + r) * 1024 + bd + c4 * 4) = o;
  }
}

// ---------------------------------------------------------------------------
// LayerNorm over d=1024, writes bf16 x_norm. One block (256 thr) per row.
// ---------------------------------------------------------------------------
__global__ void ln_kernel(const float* __restrict__ x, const float* __restrict__ g,
                          const float* __restrict__ b, bf16* __restrict__ out) {
  const size_t row = blockIdx.x;
  const int t = threadIdx.x;
  float4 v = ((const float4*)(x + row * DM))[t];
  float s = v.x + v.y + v.z + v.w;
  float s2 = v.x*v.x + v.y*v.y + v.z*v.z + v.w*v.w;
#pragma unroll
  for (int m = 1; m < 64; m <<= 1) { s += __shfl_xor(s, m, 64); s2 += __shfl_xor(s2, m, 64); }
  __shared__ float red[8];
  int wave = t >> 6, lane = t & 63;
  if (lane == 0) { red[wave] = s; red[4 + wave] = s2; }
  __syncthreads();
  s  = red[0] + red[1] + red[2] + red[3];
  s2 = red[4] + red[5] + red[6] + red[7];
  float mu  = s * (1.f / DM);
  float var = s2 * (1.f / DM) - mu * mu;
  float inv = rsqrtf(var + 1e-5f);
  float4 gg = ((const float4*)g)[t];
  float4 bb = ((const float4*)b)[t];
  bf16x4 o;
  o.x = (bf16)((v.x - mu) * inv * gg.x + bb.x);
  o.y = (bf16)((v.y - mu) * inv * gg.y + bb.y);
  o.z = (bf16)((v.z - mu) * inv * gg.z + bb.z);
  o.w = (bf16)((v.w - mu) * inv * gg.w + bb.w);
  *(bf16x4*)(out + row * DM + t * 4) = o;
}

// ---------------------------------------------------------------------------
// MFMA bf16 GEMM: C[M,N] = A[M,K] @ W[N,K]^T. 128x128 tile, BK=64 (two 32-wide
// sub-stages per barrier pair). LDS k-chunks XOR-swizzled by (row>>1)&3 so
// ds_read_b128 fragments hit all 32 banks 2-way.
// SWZ grid: blk%8 = XCD -> 8-m-tile stripe per XCD (A-stripe L2-resident).
// ---------------------------------------------------------------------------
template <int EPI, bool SWZ>
__global__ __launch_bounds__(256)
void gemm_bf16(const bf16* __restrict__ A, const bf16* __restrict__ W, int K,
               float* __restrict__ out_f, bf16* __restrict__ out_b,
               u16* __restrict__ out_u1, u16* __restrict__ out_u2,
               const float* __restrict__ aux,
               float* __restrict__ out_f3, float* __restrict__ out_f4) {
  __shared__ bf16 As[2][128 * 32];
  __shared__ bf16 Bs[2][128 * 32];
  int tx, ty;
  if (SWZ) {
    int g = blockIdx.x;           // total = 8 XCD * 8 mloc * ntx
    int xcd = g & 7, slot = g >> 3;
    tx = slot >> 3;               // n-tile (n-major sweep within XCD)
    ty = xcd * 8 + (slot & 7);    // m-tile within this XCD's stripe
  } else {
    tx = blockIdx.x; ty = blockIdx.y;
  }
  const int tid  = threadIdx.x;
  const int wave = tid >> 6, lane = tid & 63;
  const int lr = lane & 15, quad = lane >> 4;
  const size_t arow = (size_t)ty * 128;
  const size_t brow = (size_t)tx * 128;
  f32x4 acc[4][4] = {};

  const int srl  = lane >> 2;          // row-local 0..15
  const int kg   = lane & 3;           // k-group 0..3
  const int srow = wave * 32 + srl;
  const int skc  = (kg ^ ((srl >> 1) & 3)) * 8;   // swizzled global k-offset
  const bf16* ag = A + (arow + srow) * (size_t)K + skc;
  const bf16* wg = W + (brow + srow) * (size_t)K + skc;
  bf16* asl0 = &As[0][wave * 32 * 32];
  bf16* asl1 = &As[1][wave * 32 * 32];
  bf16* bsl0 = &Bs[0][wave * 32 * 32];
  bf16* bsl1 = &Bs[1][wave * 32 * 32];

  const int rk = (quad ^ ((lr >> 1) & 3)) * 8;

  for (int k0 = 0; k0 < K; k0 += 64) {
    async16(ag + k0,                       asl0);
    async16(ag + (size_t)16 * K + k0,      asl0 + 16 * 32);
    async16(ag + k0 + 32,                  asl1);
    async16(ag + (size_t)16 * K + k0 + 32, asl1 + 16 * 32);
    async16(wg + k0,                       bsl0);
    async16(wg + (size_t)16 * K + k0,      bsl0 + 16 * 32);
    async16(wg + k0 + 32,                  bsl1);
    async16(wg + (size_t)16 * K + k0 + 32, bsl1 + 16 * 32);
    __syncthreads();
#pragma unroll
    for (int kh = 0; kh < 2; ++kh) {
      const bf16* ap = &As[kh][(((wave >> 1) * 64) + lr) * 32 + rk];
      const bf16* bp = &Bs[kh][(((wave & 1) * 64) + lr) * 32 + rk];
      bf16x8 af[4], bfr[4];
#pragma unroll
      for (int i = 0; i < 4; ++i) af[i] = *(const bf16x8*)(ap + i * 16 * 32);
#pragma unroll
      for (int j = 0; j < 4; ++j) bfr[j] = *(const bf16x8*)(bp + j * 16 * 32);
#pragma unroll
      for (int i = 0; i < 4; ++i)
#pragma unroll
        for (int j = 0; j < 4; ++j)
          acc[i][j] = __builtin_amdgcn_mfma_f32_16x16x32_bf16(af[i], bfr[j], acc[i][j], 0, 0, 0);
    }
    __syncthreads();
  }

  // Epilogue. D layout (verified m89/m91): col = lane&15, row = quad*4 + reg.
  const size_t mbase = arow + (wave >> 1) * 64;
  const size_t nbase = brow + (wave & 1) * 64;
  if (EPI == 0) {
    if (nbase < DM) {                       // xi region
#pragma unroll
      for (int i = 0; i < 4; ++i)
#pragma unroll
        for (int j = 0; j < 4; ++j)
#pragma unroll
          for (int r = 0; r < 4; ++r) {
            size_t m = mbase + i * 16 + quad * 4 + r;
            size_t n = nbase + j * 16 + lr;
            out_u1[m * DM + n] = __builtin_bit_cast(u16, (bf16)acc[i][j][r]);
          }
    } else if (nbase < 2 * DM) {            // z region
#pragma unroll
      for (int i = 0; i < 4; ++i)
#pragma unroll
        for (int j = 0; j < 4; ++j)
#pragma unroll
          for (int r = 0; r < 4; ++r) {
            size_t m = mbase + i * 16 + quad * 4 + r;
            size_t n = nbase - DM + j * 16 + lr;
            out_b[m * DM + n] = (bf16)acc[i][j][r];
          }
    } else if (nbase < 3 * DM) {            // dt region (softplus)
#pragma unroll
      for (int i = 0; i < 4; ++i)
#pragma unroll
        for (int j = 0; j < 4; ++j)
#pragma unroll
          for (int r = 0; r < 4; ++r) {
            size_t m = mbase + i * 16 + quad * 4 + r;
            size_t n = nbase - 2 * DM + j * 16 + lr;
            float tt = acc[i][j][r] + aux[n];
            float sp = (tt > 20.f) ? tt : __logf(1.f + __expf(tt));
            out_u2[m * DM + n] = __builtin_bit_cast(u16, (bf16)sp);
          }
    } else if (nbase < 3 * DM + 2 * NS) {   // B/C region (j==0 -> B, j==1 -> C)
#pragma unroll
      for (int i = 0; i < 4; ++i)
#pragma unroll
        for (int r = 0; r < 4; ++r) {
          size_t m = mbase + i * 16 + quad * 4 + r;
          out_f3[m * NS + lr] = acc[i][0][r];
          out_f4[m * NS + lr] = acc[i][1][r];
        }
    } // else: garbage pad columns, discard
  } else {
#pragma unroll
    for (int i = 0; i < 4; ++i)
#pragma unroll
      for (int j = 0; j < 4; ++j)
#pragma unroll
        for (int r = 0; r < 4; ++r) {
          size_t m = mbase + i * 16 + quad * 4 + r;
          size_t n = nbase + j * 16 + lr;
          float v = acc[i][j][r];
          if (EPI == 2) {
            out_f[m * DM + n] = v + aux[m * DM + n];
          } else {
            out_b[m * (size_t)DM + n] = (bf16)v;
          }
        }
  }
}

// ---------------------------------------------------------------------------
// Segmented scan pass 1: per (seg, b, 16 d-channels), thread (dl,n) runs the
// 128-step local recurrence from h=0, tracking decay product P. Writes
// h_end and P per state. All inputs staged once; b128-batched hot loop.
// ---------------------------------------------------------------------------
__global__ __launch_bounds__(256)
void scan_pass1(const u16* __restrict__ dt_b, const u16* __restrict__ xi_b,
                const float* __restrict__ B_t, const float* __restrict__ A_log,
                float* __restrict__ hend, float* __restrict__ pprod) {
  int s, b, d0; seg_decode(blockIdx.x, s, b, d0);
  const int t = threadIdx.x;
  const int n = t & 15, dl = t >> 4;
  const float Ac2 = -__expf(A_log[(d0 + dl) * NS + n]) * 1.44269504f;

  __shared__ u32   dxs[16][ROWP];   // packed (dt,xi): [chan][l]
  __shared__ float Bsh[16][ROWP];   // [n][l]

  const size_t base_row = (size_t)b * LSEQ + (size_t)s * SEGL;
  const int l_a = t >> 4, c_a = t & 15;
#pragma unroll
  for (int k = 0; k < 8; ++k) {
    int l = l_a + 16 * k;
    size_t ga = (base_row + l) * DM + d0 + c_a;
    dxs[c_a][l] = (u32)dt_b[ga] | ((u32)xi_b[ga] << 16);
  }
#pragma unroll
  for (int k = 0; k < 2; ++k) {
    int idx = t + 256 * k;          // 512 float4 = 128 rows x 16 n
    int l = idx >> 2, j4 = (idx & 3) * 4;
    float4 v = *(const float4*)(B_t + (base_row + l) * NS + j4);
    Bsh[j4 + 0][l] = v.x; Bsh[j4 + 1][l] = v.y;
    Bsh[j4 + 2][l] = v.z; Bsh[j4 + 3][l] = v.w;
  }
  __syncthreads();

  float h = 0.f, P = 1.f;
#pragma unroll 4
  for (int l4 = 0; l4 < SEGL; l4 += 4) {
    u32x4 dx4 = *(const u32x4*)&dxs[dl][l4];
    f32x4 b4  = *(const f32x4*)&Bsh[n][l4];
#pragma unroll
    for (int i = 0; i < 4; ++i) {
      float dtv = bflo(dx4[i]), xiv = bfhi(dx4[i]);
      float a = __builtin_amdgcn_exp2f(dtv * Ac2);
      h = fmaf(a, h, (dtv * xiv) * b4[i]);
      P *= a;
    }
  }
  size_t idx = ((size_t)(s * 8 + b)) * (DM * NS) + d0 * 16 + t;
  hend[idx] = h;
  pprod[idx] = P;
}

// ---------------------------------------------------------------------------
// Combine: serial over 8 segments in registers. Writes per-segment true
// h_start and the final hidden state.
// ---------------------------------------------------------------------------
__global__ void scan_combine(const float* __restrict__ h_prev,
                             const float* __restrict__ hend,
                             const float* __restrict__ pprod,
                             float* __restrict__ hstart,
                             float* __restrict__ h_final) {
  size_t gid = (size_t)blockIdx.x * 256 + threadIdx.x;   // 131072 states
  int b = (int)(gid >> 14);
  size_t j = gid & 16383;
  float hs = h_prev[gid];
#pragma unroll
  for (int s = 0; s < NSEG; ++s) {
    size_t idx = ((size_t)(s * 8 + b)) * (DM * NS) + j;
    hstart[idx] = hs;
    hs = fmaf(pprod[idx], hs, hend[idx]);
  }
  h_final[gid] = hs;
}

// ---------------------------------------------------------------------------
// Segmented scan pass 2: re-runs each segment from the true h_start, DPP
// row-reduction for y, fused silu(z) gate + D-term, writes ssm_out bf16.
// ---------------------------------------------------------------------------
__global__ __launch_bounds__(256)
void scan_pass2(const u16* __restrict__ dt_b, const u16* __restrict__ xi_b,
                const bf16* __restrict__ z_b,
                const float* __restrict__ B_t, const float* __restrict__ C_t,
                const float* __restrict__ A_log, const float* __restrict__ hstart,
                const float* __restrict__ Dvec, bf16* __restrict__ ssm_out) {
  int s, b, d0; seg_decode(blockIdx.x, s, b, d0);
  const int t = threadIdx.x;
  const int n = t & 15, dl = t >> 4;
  const float Ac2 = -__expf(A_log[(d0 + dl) * NS + n]) * 1.44269504f;

  __shared__ u32   dxs[16][ROWP];   // packed (dt,xi): [chan][l]
  __shared__ float Bsh[16][ROWP];   // [n][l]
  __shared__ float Csh[16][ROWP];   // [n][l]
  __shared__ float ys[SEGL][17];    // y[l][chan]

  const size_t base_row = (size_t)b * LSEQ + (size_t)s * SEGL;
  const int l_a = t >> 4, c_a = t & 15;
#pragma unroll
  for (int k = 0; k < 8; ++k) {
    int l = l_a + 16 * k;
    size_t ga = (base_row + l) * DM + d0 + c_a;
    dxs[c_a][l] = (u32)dt_b[ga] | ((u32)xi_b[ga] << 16);
  }
#pragma unroll
  for (int k = 0; k < 2; ++k) {
    int idx = t + 256 * k;
    int l = idx >> 2, j4 = (idx & 3) * 4;
    float4 v = *(const float4*)(B_t + (base_row + l) * NS + j4);
    Bsh[j4 + 0][l] = v.x; Bsh[j4 + 1][l] = v.y;
    Bsh[j4 + 2][l] = v.z; Bsh[j4 + 3][l] = v.w;
    float4 w = *(const float4*)(C_t + (base_row + l) * NS + j4);
    Csh[j4 + 0][l] = w.x; Csh[j4 + 1][l] = w.y;
    Csh[j4 + 2][l] = w.z; Csh[j4 + 3][l] = w.w;
  }
  float h = hstart[((size_t)(s * 8 + b)) * (DM * NS) + d0 * 16 + t];
  __syncthreads();

#pragma unroll 4
  for (int l4 = 0; l4 < SEGL; l4 += 4) {
    u32x4 dx4 = *(const u32x4*)&dxs[dl][l4];
    f32x4 b4  = *(const f32x4*)&Bsh[n][l4];
    f32x4 c4  = *(const f32x4*)&Csh[n][l4];
#pragma unroll
    for (int i = 0; i < 4; ++i) {
      float dtv = bflo(dx4[i]), xiv = bfhi(dx4[i]);
      float a = __builtin_amdgcn_exp2f(dtv * Ac2);
      h = fmaf(a, h, (dtv * xiv) * b4[i]);
      float p = row_reduce16(h * c4[i]);
      if (n == 0) ys[l4 + i][dl] = p;
    }
  }
  __syncthreads();

  // output: thread (l_a, c_a) handles rows l_a+16k, channel c_a
  const float Dva = Dvec[d0 + c_a];
#pragma unroll
  for (int k = 0; k < 8; ++k) {
    int l = l_a + 16 * k;
    size_t grow = base_row + l;
    float zv = (float)z_b[grow * DM + d0 + c_a];
    float gate = zv / (1.f + __expf(-zv));
    float xi = bfhi(dxs[c_a][l]);
    ssm_out[grow * DM + d0 + c_a] = (bf16)(ys[l][c_a] * gate + xi * Dva);
  }
}

// ---------------------------------------------------------------------------
extern "C" void kernel_launch(void* const* d_in, const int* in_sizes, int n_in,
                              void* d_out, int out_size, void* d_ws, size_t ws_size,
                              hipStream_t stream) {
  const float* x      = (const float*)d_in[0];
  const float* h_prev = (const float*)d_in[1];
  const float* ln_g   = (const float*)d_in[2];
  const float* ln_b   = (const float*)d_in[3];
  const float* W_ig   = (const float*)d_in[4];
  const float* W_dt   = (const float*)d_in[5];
  const float* b_dt   = (const float*)d_in[6];
  const float* A_log  = (const float*)d_in[7];
  const float* W_B    = (const float*)d_in[8];
  const float* W_C    = (const float*)d_in[9];
  const float* Dvec   = (const float*)d_in[10];
  const float* W_out  = (const float*)d_in[11];

  char* ws = (char*)d_ws;
  size_t off = 0;
  auto alloc = [&](size_t bytes) -> char* {
    char* p = ws + off;
    off += (bytes + 255) & ~(size_t)255;
    return p;
  };
  bf16*  wmega_b = (bf16*)alloc((size_t)3200 * DM * 2);       // 6.25 MB
  bf16*  wstack_b= (bf16*)alloc((size_t)1152 * DM * 2);       // 2.25 MB
  bf16*  wigT_b  = (bf16*)alloc((size_t)DM * DM * 2);         // 2 MB
  bf16*  wout_b  = (bf16*)alloc((size_t)DM * DM * 2);         // 2 MB
  bf16*  xnorm_b = (bf16*)alloc((size_t)MROWS * DM * 2);      // 16 MB
  u16*   xi_w    = (u16*)alloc((size_t)MROWS * DM * 2);       // 16 MB bf16 xi
  u16*   dt_w    = (u16*)alloc((size_t)MROWS * DM * 2);       // 16 MB bf16 dt
  bf16*  z_bb    = (bf16*)alloc((size_t)MROWS * DM * 2);      // 16 MB
  bf16*  ssm_b   = (bf16*)alloc((size_t)MROWS * DM * 2);      // 16 MB
  float* Bt      = (float*)alloc((size_t)MROWS * NS * 4);     // 0.5 MB
  float* Ct      = (float*)alloc((size_t)MROWS * NS * 4);     // 0.5 MB
  float* hend_w  = (float*)alloc((size_t)NSEG * DM * NS * BSZ * 4); // 4 MB
  float* pprod_w = (float*)alloc((size_t)NSEG * DM * NS * BSZ * 4); // 4 MB
  float* hstart_w= (float*)alloc((size_t)NSEG * DM * NS * BSZ * 4); // 4 MB
  (void)ws_size; (void)in_sizes; (void)n_in; (void)out_size;

  float* out_main = (float*)d_out;
  float* out_h    = (float*)d_out + (size_t)MROWS * DM;

  // 1) weight casts
  cast_f2b<<<(2 * DM * DM / 4 + 255) / 256, 256, 0, stream>>>(W_ig, wmega_b, 2 * DM * DM / 4);
  cast_f2b<<<(DM * DM / 4 + 255) / 256, 256, 0, stream>>>(W_dt, wstack_b, DM * DM / 4);
  cast_f2b<<<(NS * DM / 4 + 255) / 256, 256, 0, stream>>>(W_B, wstack_b + (size_t)DM * DM, NS * DM / 4);
  cast_f2b<<<(NS * DM / 4 + 255) / 256, 256, 0, stream>>>(W_C, wstack_b + (size_t)(DM + NS) * DM, NS * DM / 4);
  cast_f2b<<<(DM * DM / 4 + 255) / 256, 256, 0, stream>>>(W_out, wout_b, DM * DM / 4);
  // 2) W_ig[:1024]^T (for weight composition)
  transpose_cast<<<dim3(16, 16), 256, 0, stream>>>(W_ig, wigT_b);

  // 3) layernorm -> bf16
  ln_kernel<<<MROWS, 256, 0, stream>>>(x, ln_g, ln_b, xnorm_b);

  // 4) compose: wmega[2048+e][k] = sum_d [Wdt;WB;WC][e][d] * W_ig[d][k]
  gemm_bf16<3, false><<<dim3(8, 9), 256, 0, stream>>>(wstack_b, wigT_b, DM,
      nullptr, wmega_b + (size_t)2048 * DM, nullptr, nullptr, nullptr, nullptr, nullptr);

  // 5) mega GEMM (M=8192, N=3104(pad 3200), K=1024), XCD-swizzled 1D grid:
  //    writes xi, z, dt, B_t, C_t
  gemm_bf16<0, true><<<1600, 256, 0, stream>>>(xnorm_b, wmega_b, DM,
      nullptr, z_bb, xi_w, dt_w, b_dt, Bt, Ct);

  // 6) segmented selective scan: pass1 -> combine -> pass2 (fused gate)
  scan_pass1<<<4096, 256, 0, stream>>>(dt_w, xi_w, Bt, A_log, hend_w, pprod_w);
  scan_combine<<<512, 256, 0, stream>>>(h_prev, hend_w, pprod_w, hstart_w, out_h);
  scan_pass2<<<4096, 256, 0, stream>>>(dt_w, xi_w, z_bb, Bt, Ct, A_log,
                                       hstart_w, Dvec, ssm_b);

  // 7) output GEMM (M=8192, N=1024, K=1024) + residual x, XCD-swizzled
  gemm_bf16<2, true><<<512, 256, 0, stream>>>(ssm_b, wout_b, DM,
      out_main, nullptr, nullptr, nullptr, x, nullptr, nullptr);
}